// Round 11
// baseline (226.628 us; speedup 1.0000x reference)
//
#include <hip/hip_runtime.h>

#define B_DIM 1024
#define S_DIM 16
#define H_DIM 1024
#define N_DIM 16384
#define L_DIM 128
#define KX    (H_DIM + L_DIM)   // 1152, divisible by 64

typedef __bf16 bf16_8 __attribute__((ext_vector_type(8)));
typedef float  f32x4  __attribute__((ext_vector_type(4)));

// round-to-nearest-even f32 -> bf16 (bit trick; inputs finite)
__device__ __forceinline__ unsigned short f2bf(float f) {
    unsigned int u = __float_as_uint(f);
    u += 0x7fffu + ((u >> 16) & 1u);
    return (unsigned short)(u >> 16);
}

// async global -> LDS, 16 B per lane (dest must be uniform-base + lane*16)
#define GLD16(gp, lp)                                                          \
    __builtin_amdgcn_global_load_lds(                                          \
        (const __attribute__((address_space(1))) void*)(gp),                   \
        (__attribute__((address_space(3))) void*)(lp), 16, 0, 0)

// ---------------------------------------------------------------------------
// Kernel 1: label aggregation. Rounds 1-6 established: scattered LDS RMW
// (atomic or not) runs at ~105 cy/wave-op because each read->write->read
// chain exposes full LDS latency. Fix: ROTATED COLUMNS. Lane t, element
// counter i uses column (t+i)&63 of bins[label][64]. Aliasing between two
// ops of a lane requires same label AND di % 64 == 0 -> impossible inside
// a 64-element window. So each 16-element batch = 16 independent ds_reads,
// 16 adds, 16 ds_writes: the LDS pipe streams at throughput, no hazards.
// Bank = (label*64 + col)%32 = col%32: 2 lanes/bank, conflict-free.
// ---------------------------------------------------------------------------
__global__ __launch_bounds__(64) void k_agg(
    const float* __restrict__ feats,   // (B, S, H)
    const float* __restrict__ sims,    // (B, N)
    const int*   __restrict__ labels,  // (B, N)
    unsigned short* __restrict__ xin)  // (B, KX) bf16
{
    __shared__ float bins[L_DIM * 64];  // 32 KB -> 4 blocks/CU
    const int bb = blockIdx.x;
    const int t  = threadIdx.x;         // 0..63

    #pragma unroll
    for (int i = 0; i < L_DIM; ++i) bins[i * 64 + t] = 0.f;
    __syncthreads();

    const float4* s4 = (const float4*)(sims   + (size_t)bb * N_DIM);
    const int4*   l4 = (const int4*)  (labels + (size_t)bb * N_DIM);

    float4 fs[2][4];
    int4   fl[2][4];

#define LOADB(slot, bt)                                                        \
    do {                                                                       \
        _Pragma("unroll")                                                      \
        for (int q = 0; q < 4; ++q) {                                          \
            fs[slot][q] = s4[((bt) * 4 + q) * 64 + t];                         \
            fl[slot][q] = l4[((bt) * 4 + q) * 64 + t];                         \
        }                                                                      \
    } while (0)

    LOADB(0, 0);
    LOADB(1, 1);
    #pragma unroll
    for (int bt = 0; bt < 16; ++bt) {
        const int sl = bt & 1;
        int   ad[16];
        float vv[16], rr[16];
        // address/value extraction (pure VALU)
        #pragma unroll
        for (int q = 0; q < 4; ++q) {
            const int*   lp = (const int*)  &fl[sl][q];
            const float* sp = (const float*)&fs[sl][q];
            #pragma unroll
            for (int k = 0; k < 4; ++k) {
                const int e   = q * 4 + k;          // 0..15
                const int i   = bt * 16 + e;        // lane-local counter
                const int col = (t + i) & 63;       // rotated column
                ad[e] = lp[k] * 64 + col;
                vv[e] = sp[k];
            }
        }
        // 16 independent reads -> 16 adds -> 16 independent writes
        #pragma unroll
        for (int e = 0; e < 16; ++e) rr[e] = bins[ad[e]];
        #pragma unroll
        for (int e = 0; e < 16; ++e) bins[ad[e]] = rr[e] + vv[e];
        if (bt + 2 < 16) LOADB(sl, bt + 2);
    }
    __syncthreads();

    unsigned short* xrow = xin + (size_t)bb * KX;
    // cls = features[bb, 0, :]: 1024 floats = 256 float4, 4 per lane
    const float4* c4 = (const float4*)(feats + (size_t)bb * (S_DIM * H_DIM));
    #pragma unroll
    for (int i = 0; i < 4; ++i) {
        float4 cv = c4[t + i * 64];
        ushort4 p;
        p.x = f2bf(cv.x); p.y = f2bf(cv.y); p.z = f2bf(cv.z); p.w = f2bf(cv.w);
        *(ushort4*)(xrow + (t + i * 64) * 4) = p;
    }

    // reduce 64 columns per bin; lane handles bins t and t+64; skewed banks
    #pragma unroll
    for (int pb = 0; pb < 2; ++pb) {
        const int l = pb * 64 + t;
        float a0 = 0.f, a1 = 0.f, a2 = 0.f, a3 = 0.f;
        #pragma unroll
        for (int i = 0; i < 64; i += 4) {
            a0 += bins[l * 64 + ((t + i)     & 63)];
            a1 += bins[l * 64 + ((t + i + 1) & 63)];
            a2 += bins[l * 64 + ((t + i + 2) & 63)];
            a3 += bins[l * 64 + ((t + i + 3) & 63)];
        }
        xrow[H_DIM + l] = f2bf((a0 + a1 + a2 + a3) * (1.0f / N_DIM));
    }
#undef LOADB
}

// ---------------------------------------------------------------------------
// Kernel 2: f32 -> bf16 conversion of both weight matrices (grid-stride)
// ---------------------------------------------------------------------------
__global__ __launch_bounds__(256) void k_cvt(
    const float* __restrict__ w1, const float* __restrict__ w2,
    unsigned short* __restrict__ o1, unsigned short* __restrict__ o2,
    int n1v, int n2v)  // counts in float4 units
{
    int idx = blockIdx.x * 256 + threadIdx.x;
    int stride = gridDim.x * 256;
    for (int i = idx; i < n1v + n2v; i += stride) {
        const float4* src; unsigned short* dst; int j;
        if (i < n1v) { src = (const float4*)w1; dst = o1; j = i; }
        else         { src = (const float4*)w2; dst = o2; j = i - n1v; }
        float4 v = src[j];
        ushort4 p;
        p.x = f2bf(v.x); p.y = f2bf(v.y); p.z = f2bf(v.z); p.w = f2bf(v.w);
        *(ushort4*)(dst + j * 4) = p;
    }
}

// ---------------------------------------------------------------------------
// bf16 MFMA GEMM, C = A(MxK) . B(NxK)^T, both row-major, K contiguous.
// 128x64 tile, BK=64, 4 waves: wave w owns rows [w*32, w*32+32) x 64 cols
// = 2x4 frags of 16x16x32 -> 16 MFMA + 12 ds_read_b128 per K-step.
// Staging: global_load_lds 16B, XOR-swizzled SOURCE granule (g ^= row&7),
// linear LDS dest + swizzled ds_read (G21 both-sides) -> conflict-free b128.
// Pipeline: 3 LDS buffers, 2-deep prefetch, counted vmcnt (never 0 mid-loop).
// SWZ=1: 1-D grid, bijective XCD decode (T1) so the 8 M-blocks sharing one
// B n-tile land on one XCD -> B is L2-resident, A fetched once per XCD.
// EPI=0: bias+tanh -> bf16; EPI=1: bias -> f32.
// ---------------------------------------------------------------------------
template <int EPI, int SWZ>
__global__ __launch_bounds__(256) void k_gemm(
    const unsigned short* __restrict__ A,   // M x K bf16
    const unsigned short* __restrict__ Bm,  // N x K bf16
    const float* __restrict__ bias,         // N
    void* __restrict__ Cout,
    int M, int N, int K, int ldc)
{
    __shared__ __align__(16) unsigned short smA[3][128 * 64];  // 48 KB
    __shared__ __align__(16) unsigned short smB[3][64 * 64];   // 24 KB

    const int t    = threadIdx.x;
    const int lane = t & 63;
    const int w    = t >> 6;
    int m0, n0;
    if (SWZ) {
        // d&7 = XCD (dispatch round-robin); ntile = (d&7) + ((d>>6)<<3);
        // mtile = (d>>3)&7. Bijective for grid 128 = 16 ntiles x 8 mtiles.
        const int d = blockIdx.x;
        n0 = (((d & 7) | ((d >> 6) << 3))) * 64;
        m0 = ((d >> 3) & 7) * 128;
    } else {
        m0 = blockIdx.y * 128;
        n0 = blockIdx.x * 64;
    }
    const int lr   = lane & 15;
    const int hi   = lane >> 4;
    const int sw   = lr & 7;          // per-lane read swizzle

    // pre-swizzled global source offsets (elements)
    int srcA[4], srcB[2];
    #pragma unroll
    for (int j = 0; j < 4; ++j) {
        int idx = t + j * 256;              // A granule 0..1023
        int row = idx >> 3;
        int g   = (idx & 7) ^ (row & 7);
        srcA[j] = row * K + g * 8;
    }
    #pragma unroll
    for (int j = 0; j < 2; ++j) {
        int idx = t + j * 256;              // B granule 0..511
        int row = idx >> 3;
        int g   = (idx & 7) ^ (row & 7);
        srcB[j] = row * K + g * 8;
    }
    const size_t aBase = (size_t)m0 * K;
    const size_t bBase = (size_t)n0 * K;

    const int nt = K >> 6;
    f32x4 acc[2][4] = {};

#define STAGE(buf, k0_)                                                        \
    do {                                                                       \
        _Pragma("unroll")                                                      \
        for (int j = 0; j < 4; ++j)                                            \
            GLD16(A + aBase + (size_t)(srcA[j] + (k0_)),                       \
                  &smA[buf][(t + j * 256) * 8]);                               \
        _Pragma("unroll")                                                      \
        for (int j = 0; j < 2; ++j)                                            \
            GLD16(Bm + bBase + (size_t)(srcB[j] + (k0_)),                      \
                  &smB[buf][(t + j * 256) * 8]);                               \
    } while (0)

    STAGE(0, 0);
    if (nt > 1) STAGE(1, 64);

    int cur = 0;
    for (int ti = 0; ti < nt; ++ti) {
        int b2 = cur + 2; if (b2 >= 3) b2 -= 3;
        if (ti + 2 < nt) {
            STAGE(b2, (ti + 2) << 6);
            asm volatile("s_waitcnt vmcnt(12)" ::: "memory");
        } else if (ti + 1 < nt) {
            asm volatile("s_waitcnt vmcnt(6)" ::: "memory");
        } else {
            asm volatile("s_waitcnt vmcnt(0)" ::: "memory");
        }
        __builtin_amdgcn_s_barrier();
        asm volatile("" ::: "memory");

        const unsigned short* As = smA[cur];
        const unsigned short* Bs = smB[cur];
        #pragma unroll
        for (int ks = 0; ks < 2; ++ks) {
            const int ga = ((ks * 4 + hi) ^ sw) * 8;   // swizzled elem offset
            bf16_8 a0 = *(const bf16_8*)(As + (w * 32 +      lr) * 64 + ga);
            bf16_8 a1 = *(const bf16_8*)(As + (w * 32 + 16 + lr) * 64 + ga);
            bf16_8 b0 = *(const bf16_8*)(Bs + (      lr) * 64 + ga);
            bf16_8 b1 = *(const bf16_8*)(Bs + (16  + lr) * 64 + ga);
            bf16_8 b2v = *(const bf16_8*)(Bs + (32 + lr) * 64 + ga);
            bf16_8 b3 = *(const bf16_8*)(Bs + (48  + lr) * 64 + ga);
            acc[0][0] = __builtin_amdgcn_mfma_f32_16x16x32_bf16(a0, b0,  acc[0][0], 0, 0, 0);
            acc[1][0] = __builtin_amdgcn_mfma_f32_16x16x32_bf16(a1, b0,  acc[1][0], 0, 0, 0);
            acc[0][1] = __builtin_amdgcn_mfma_f32_16x16x32_bf16(a0, b1,  acc[0][1], 0, 0, 0);
            acc[1][1] = __builtin_amdgcn_mfma_f32_16x16x32_bf16(a1, b1,  acc[1][1], 0, 0, 0);
            acc[0][2] = __builtin_amdgcn_mfma_f32_16x16x32_bf16(a0, b2v, acc[0][2], 0, 0, 0);
            acc[1][2] = __builtin_amdgcn_mfma_f32_16x16x32_bf16(a1, b2v, acc[1][2], 0, 0, 0);
            acc[0][3] = __builtin_amdgcn_mfma_f32_16x16x32_bf16(a0, b3,  acc[0][3], 0, 0, 0);
            acc[1][3] = __builtin_amdgcn_mfma_f32_16x16x32_bf16(a1, b3,  acc[1][3], 0, 0, 0);
        }

        asm volatile("" ::: "memory");
        __builtin_amdgcn_s_barrier();
        cur = cur + 1; if (cur >= 3) cur = 0;
    }

    // epilogue: C/D layout col = lane&15, row = (lane>>4)*4 + reg  [m89]
    const int rbase = m0 + w * 32 + hi * 4;
    const int cbase = n0 + lr;
    #pragma unroll
    for (int i = 0; i < 2; ++i) {
        #pragma unroll
        for (int j = 0; j < 4; ++j) {
            int col = cbase + j * 16;
            float bv = bias[col];
            #pragma unroll
            for (int r = 0; r < 4; ++r) {
                int row = rbase + i * 16 + r;
                float v = acc[i][j][r] + bv;
                if (EPI == 0) {
                    v = tanhf(v);
                    ((unsigned short*)Cout)[(size_t)row * ldc + col] = f2bf(v);
                } else {
                    ((float*)Cout)[(size_t)row * ldc + col] = v;
                }
            }
        }
    }
#undef STAGE
}

// ---------------------------------------------------------------------------
extern "C" void kernel_launch(void* const* d_in, const int* in_sizes, int n_in,
                              void* d_out, int out_size, void* d_ws, size_t ws_size,
                              hipStream_t stream) {
    const float* feats   = (const float*)d_in[0];
    const float* sims    = (const float*)d_in[1];
    const int*   labels  = (const int*)  d_in[2];
    const float* dense_w = (const float*)d_in[3];
    const float* dense_b = (const float*)d_in[4];
    const float* out_w   = (const float*)d_in[5];
    const float* out_b   = (const float*)d_in[6];
    float* out = (float*)d_out;

    // workspace layout (bf16 buffers), total ~7.1 MB
    unsigned short* xin  = (unsigned short*)d_ws;               // B x KX
    unsigned short* wd   = xin  + (size_t)B_DIM * KX;           // H x KX
    unsigned short* wo   = wd   + (size_t)H_DIM * KX;           // L x H
    unsigned short* xmid = wo   + (size_t)L_DIM * H_DIM;        // B x H

    k_agg<<<B_DIM, 64, 0, stream>>>(feats, sims, labels, xin);

    int n1v = (H_DIM * KX) / 4;
    int n2v = (L_DIM * H_DIM) / 4;
    k_cvt<<<512, 256, 0, stream>>>(dense_w, out_w, wd, wo, n1v, n2v);

    // gemm1: 1-D grid 128 = 16 ntiles x 8 mtiles, XCD-swizzled decode
    k_gemm<0, 1><<<128, 256, 0, stream>>>(xin, wd, dense_b, (void*)xmid,
                                          B_DIM, H_DIM, KX, H_DIM);

    dim3 g2(L_DIM / 64, B_DIM / 128);   // (2, 8) = 16 blocks
    k_gemm<1, 0><<<g2, 256, 0, stream>>>(xmid, wo, out_b, (void*)out,
                                         B_DIM, L_DIM, H_DIM, L_DIM);
}

// Round 13
// 216.758 us; speedup vs baseline: 1.0455x; 1.0455x over previous
//
#include <hip/hip_runtime.h>

#define B_DIM 1024
#define S_DIM 16
#define H_DIM 1024
#define N_DIM 16384
#define L_DIM 128
#define KX    (H_DIM + L_DIM)   // 1152, divisible by 64

typedef __bf16 bf16_8 __attribute__((ext_vector_type(8)));
typedef float  f32x4  __attribute__((ext_vector_type(4)));

__device__ __forceinline__ unsigned short f2bf(float f) {
    unsigned int u = __float_as_uint(f);
    u += 0x7fffu + ((u >> 16) & 1u);
    return (unsigned short)(u >> 16);
}

#define GLD16(gp, lp)                                                          \
    __builtin_amdgcn_global_load_lds(                                          \
        (const __attribute__((address_space(1))) void*)(gp),                   \
        (__attribute__((address_space(3))) void*)(lp), 16, 0, 0)

// ---------------------------------------------------------------------------
// Kernel 1: label aggregation, rotated-column hazard-free LDS RMW (R11: 65us,
// was 90). R11 diagnosis: latency-bound on global loads (1 wave/SIMD, only
// 256B in flight). Fix: 4-deep LOADB prefetch -> 512B/wave outstanding,
// covers ~900cy HBM latency across ~4 batches of LDS work.
// ---------------------------------------------------------------------------
__global__ __launch_bounds__(64) void k_agg(
    const float* __restrict__ feats,   // (B, S, H)
    const float* __restrict__ sims,    // (B, N)
    const int*   __restrict__ labels,  // (B, N)
    unsigned short* __restrict__ xin)  // (B, KX) bf16
{
    __shared__ float bins[L_DIM * 64];  // 32 KB -> 4 blocks/CU
    const int bb = blockIdx.x;
    const int t  = threadIdx.x;         // 0..63

    #pragma unroll
    for (int i = 0; i < L_DIM; ++i) bins[i * 64 + t] = 0.f;
    __syncthreads();

    const float4* s4 = (const float4*)(sims   + (size_t)bb * N_DIM);
    const int4*   l4 = (const int4*)  (labels + (size_t)bb * N_DIM);

    float4 fs[4][4];
    int4   fl[4][4];

#define LOADB(slot, bt)                                                        \
    do {                                                                       \
        _Pragma("unroll")                                                      \
        for (int q = 0; q < 4; ++q) {                                          \
            fs[slot][q] = s4[((bt) * 4 + q) * 64 + t];                         \
            fl[slot][q] = l4[((bt) * 4 + q) * 64 + t];                         \
        }                                                                      \
    } while (0)

    LOADB(0, 0);
    LOADB(1, 1);
    LOADB(2, 2);
    LOADB(3, 3);
    #pragma unroll
    for (int bt = 0; bt < 16; ++bt) {
        const int sl = bt & 3;
        int   ad[16];
        float vv[16], rr[16];
        #pragma unroll
        for (int q = 0; q < 4; ++q) {
            const int*   lp = (const int*)  &fl[sl][q];
            const float* sp = (const float*)&fs[sl][q];
            #pragma unroll
            for (int k = 0; k < 4; ++k) {
                const int e   = q * 4 + k;          // 0..15
                const int i   = bt * 16 + e;        // lane-local counter
                const int col = (t + i) & 63;       // rotated column
                ad[e] = lp[k] * 64 + col;
                vv[e] = sp[k];
            }
        }
        #pragma unroll
        for (int e = 0; e < 16; ++e) rr[e] = bins[ad[e]];
        #pragma unroll
        for (int e = 0; e < 16; ++e) bins[ad[e]] = rr[e] + vv[e];
        if (bt + 4 < 16) LOADB(sl, bt + 4);
    }
    __syncthreads();

    unsigned short* xrow = xin + (size_t)bb * KX;
    const float4* c4 = (const float4*)(feats + (size_t)bb * (S_DIM * H_DIM));
    #pragma unroll
    for (int i = 0; i < 4; ++i) {
        float4 cv = c4[t + i * 64];
        ushort4 p;
        p.x = f2bf(cv.x); p.y = f2bf(cv.y); p.z = f2bf(cv.z); p.w = f2bf(cv.w);
        *(ushort4*)(xrow + (t + i * 64) * 4) = p;
    }

    #pragma unroll
    for (int pb = 0; pb < 2; ++pb) {
        const int l = pb * 64 + t;
        float a0 = 0.f, a1 = 0.f, a2 = 0.f, a3 = 0.f;
        #pragma unroll
        for (int i = 0; i < 64; i += 4) {
            a0 += bins[l * 64 + ((t + i)     & 63)];
            a1 += bins[l * 64 + ((t + i + 1) & 63)];
            a2 += bins[l * 64 + ((t + i + 2) & 63)];
            a3 += bins[l * 64 + ((t + i + 3) & 63)];
        }
        xrow[H_DIM + l] = f2bf((a0 + a1 + a2 + a3) * (1.0f / N_DIM));
    }
#undef LOADB
}

// ---------------------------------------------------------------------------
// Kernel 2: f32 -> bf16 conversion of both weight matrices (grid-stride)
// ---------------------------------------------------------------------------
__global__ __launch_bounds__(256) void k_cvt(
    const float* __restrict__ w1, const float* __restrict__ w2,
    unsigned short* __restrict__ o1, unsigned short* __restrict__ o2,
    int n1v, int n2v)
{
    int idx = blockIdx.x * 256 + threadIdx.x;
    int stride = gridDim.x * 256;
    for (int i = idx; i < n1v + n2v; i += stride) {
        const float4* src; unsigned short* dst; int j;
        if (i < n1v) { src = (const float4*)w1; dst = o1; j = i; }
        else         { src = (const float4*)w2; dst = o2; j = i - n1v; }
        float4 v = src[j];
        ushort4 p;
        p.x = f2bf(v.x); p.y = f2bf(v.y); p.z = f2bf(v.z); p.w = f2bf(v.w);
        *(ushort4*)(dst + j * 4) = p;
    }
}

// ---------------------------------------------------------------------------
// Kernel: fill out (1024x128 f32) with broadcast bias (for atomic split-K)
// ---------------------------------------------------------------------------
__global__ __launch_bounds__(256) void k_fill(
    float* __restrict__ out, const float* __restrict__ bias)
{
    int i4 = blockIdx.x * 256 + threadIdx.x;           // float4 index
    int c  = (i4 * 4) & (L_DIM - 1);
    float4 v = { bias[c], bias[c + 1], bias[c + 2], bias[c + 3] };
    ((float4*)out)[i4] = v;
}

// ---------------------------------------------------------------------------
// bf16 MFMA GEMM, C = A(M x K) . B(N x K)^T, 64x64 tile, BK=64, 4 waves
// (each wave one 32x32 quadrant, 2x2 frags, 16 MFMA/step). 4 LDS buffers,
// 3-deep prefetch, counted vmcnt (4 loads/STAGE -> waits 12/8/4/0).
// R11 diagnosis: old 128-block config used half the CUs (per-CU BW cap) and
// 2-deep cover < HBM latency. 256/128 blocks now cover all CUs; operands
// (2.25 MB panels) are L2-resident per XCD.
// Split-K via blockIdx.z chunks of k_len; EPI=2 accumulates with atomicAdd
// onto bias-prefilled f32 output.
// EPI=0: bias+tanh -> bf16; EPI=1: bias -> f32; EPI=2: atomicAdd f32.
// ---------------------------------------------------------------------------
template <int EPI>
__global__ __launch_bounds__(256) void k_gemm(
    const unsigned short* __restrict__ A,   // M x LDK bf16
    const unsigned short* __restrict__ Bm,  // N x LDK bf16
    const float* __restrict__ bias,         // N (EPI<2)
    void* __restrict__ Cout,
    int LDK, int k_len, int ldc)
{
    __shared__ __align__(16) unsigned short smA[4][64 * 64];  // 32 KB
    __shared__ __align__(16) unsigned short smB[4][64 * 64];  // 32 KB

    const int t    = threadIdx.x;
    const int lane = t & 63;
    const int w    = t >> 6;
    const int wm   = w >> 1, wn = w & 1;
    const int m0   = blockIdx.y * 64;
    const int n0   = blockIdx.x * 64;
    const int kch  = blockIdx.z * k_len;
    const int lr   = lane & 15;
    const int hi   = lane >> 4;
    const int sw   = lr & 7;

    // pre-swizzled global source offsets (elements): 2 granule-chunks per op
    int srcO[2];
    #pragma unroll
    for (int j = 0; j < 2; ++j) {
        int idx = t + j * 256;              // granule 0..511
        int row = idx >> 3;                 // 0..63
        int g   = (idx & 7) ^ (row & 7);
        srcO[j] = row * LDK + g * 8;
    }
    const size_t aBase = (size_t)m0 * LDK + kch;
    const size_t bBase = (size_t)n0 * LDK + kch;

    const int nt = k_len >> 6;
    f32x4 acc[2][2] = {};

#define STAGE(buf, k0_)                                                        \
    do {                                                                       \
        _Pragma("unroll")                                                      \
        for (int j = 0; j < 2; ++j) {                                          \
            GLD16(A  + aBase + (size_t)(srcO[j] + (k0_)),                      \
                  &smA[buf][(t + j * 256) * 8]);                               \
            GLD16(Bm + bBase + (size_t)(srcO[j] + (k0_)),                      \
                  &smB[buf][(t + j * 256) * 8]);                               \
        }                                                                      \
    } while (0)

    STAGE(0, 0);
    if (nt > 1) STAGE(1, 64);
    if (nt > 2) STAGE(2, 128);

    int cur = 0;
    for (int ti = 0; ti < nt; ++ti) {
        if (ti + 3 < nt) {
            STAGE((cur + 3) & 3, (ti + 3) << 6);
            asm volatile("s_waitcnt vmcnt(12)" ::: "memory");
        } else if (ti + 2 < nt) {
            asm volatile("s_waitcnt vmcnt(8)" ::: "memory");
        } else if (ti + 1 < nt) {
            asm volatile("s_waitcnt vmcnt(4)" ::: "memory");
        } else {
            asm volatile("s_waitcnt vmcnt(0)" ::: "memory");
        }
        __builtin_amdgcn_s_barrier();
        asm volatile("" ::: "memory");

        const unsigned short* As = smA[cur];
        const unsigned short* Bs = smB[cur];
        #pragma unroll
        for (int ks = 0; ks < 2; ++ks) {
            const int ga = ((ks * 4 + hi) ^ sw) * 8;
            bf16_8 a0 = *(const bf16_8*)(As + (wm * 32 +      lr) * 64 + ga);
            bf16_8 a1 = *(const bf16_8*)(As + (wm * 32 + 16 + lr) * 64 + ga);
            bf16_8 b0 = *(const bf16_8*)(Bs + (wn * 32 +      lr) * 64 + ga);
            bf16_8 b1 = *(const bf16_8*)(Bs + (wn * 32 + 16 + lr) * 64 + ga);
            acc[0][0] = __builtin_amdgcn_mfma_f32_16x16x32_bf16(a0, b0, acc[0][0], 0, 0, 0);
            acc[1][0] = __builtin_amdgcn_mfma_f32_16x16x32_bf16(a1, b0, acc[1][0], 0, 0, 0);
            acc[0][1] = __builtin_amdgcn_mfma_f32_16x16x32_bf16(a0, b1, acc[0][1], 0, 0, 0);
            acc[1][1] = __builtin_amdgcn_mfma_f32_16x16x32_bf16(a1, b1, acc[1][1], 0, 0, 0);
        }

        asm volatile("" ::: "memory");
        __builtin_amdgcn_s_barrier();
        cur = (cur + 1) & 3;
    }

    // epilogue: C/D layout col = lane&15, row = (lane>>4)*4 + reg  [m89]
    const int rbase = m0 + wm * 32 + hi * 4;
    const int cbase = n0 + wn * 32 + lr;
    #pragma unroll
    for (int i = 0; i < 2; ++i) {
        #pragma unroll
        for (int j = 0; j < 2; ++j) {
            int col = cbase + j * 16;
            float bv = (EPI < 2) ? bias[col] : 0.f;
            #pragma unroll
            for (int r = 0; r < 4; ++r) {
                int row = rbase + i * 16 + r;
                float v = acc[i][j][r] + bv;
                if (EPI == 0) {
                    v = tanhf(v);
                    ((unsigned short*)Cout)[(size_t)row * ldc + col] = f2bf(v);
                } else if (EPI == 1) {
                    ((float*)Cout)[(size_t)row * ldc + col] = v;
                } else {
                    atomicAdd(&((float*)Cout)[(size_t)row * ldc + col], v);
                }
            }
        }
    }
#undef STAGE
}

// ---------------------------------------------------------------------------
extern "C" void kernel_launch(void* const* d_in, const int* in_sizes, int n_in,
                              void* d_out, int out_size, void* d_ws, size_t ws_size,
                              hipStream_t stream) {
    const float* feats   = (const float*)d_in[0];
    const float* sims    = (const float*)d_in[1];
    const int*   labels  = (const int*)  d_in[2];
    const float* dense_w = (const float*)d_in[3];
    const float* dense_b = (const float*)d_in[4];
    const float* out_w   = (const float*)d_in[5];
    const float* out_b   = (const float*)d_in[6];
    float* out = (float*)d_out;

    unsigned short* xin  = (unsigned short*)d_ws;               // B x KX
    unsigned short* wd   = xin  + (size_t)B_DIM * KX;           // H x KX
    unsigned short* wo   = wd   + (size_t)H_DIM * KX;           // L x H
    unsigned short* xmid = wo   + (size_t)L_DIM * H_DIM;        // B x H

    k_agg<<<B_DIM, 64, 0, stream>>>(feats, sims, labels, xin);

    int n1v = (H_DIM * KX) / 4;
    int n2v = (L_DIM * H_DIM) / 4;
    k_cvt<<<512, 256, 0, stream>>>(dense_w, out_w, wd, wo, n1v, n2v);

    // prefill out with bias for the atomic split-K gemm2
    k_fill<<<(B_DIM * L_DIM / 4) / 256, 256, 0, stream>>>(out, out_b);

    // gemm1: 1024x1024 @ KX, 64x64 tiles -> (16,16,1) = 256 blocks
    dim3 g1(H_DIM / 64, B_DIM / 64, 1);
    k_gemm<0><<<g1, 256, 0, stream>>>(xin, wd, dense_b, (void*)xmid,
                                      KX, KX, H_DIM);

    // gemm2: 1024x128 @ 1024, split-K x4 (chunks of 256) -> (2,16,4) = 128
    dim3 g2(L_DIM / 64, B_DIM / 64, 4);
    k_gemm<2><<<g2, 256, 0, stream>>>(xmid, wo, out_b, (void*)out,
                                      H_DIM, H_DIM / 4, L_DIM);
}